// Round 11
// baseline (119.952 us; speedup 1.0000x reference)
//
#include <hip/hip_runtime.h>

// Fused: y1 = valid cross-corr(X,W) [4095x4095]; y2 = transposed-conv(y1,W) [4096x4096]
//   y2[i,j] = sum_{a,b} W[a,b]*y1(i-a,j-b), y1 masked to [0,4095)^2
//   y1(p,q) = W00*X[p][q] + W01*X[p][q+1] + W10*X[p+1][q] + W11*X[p+1][q+1]
//
// R6: kernel ~30.8us (4.45 TB/s) vs 21.5us floor. Issue-rate math: VALU ~9%,
// VMEM tiny -> latency-coverage limited. This version: __launch_bounds__(256,8)
// (VGPR<=64 -> 32 waves/CU guaranteed) + prefetch depth 2 (4 row-loads issued
// upfront, 2-3KB in flight per wave). Same math order as R6.

#define HD 4096
#define RB 8       // output rows per thread

typedef float f32x4 __attribute__((ext_vector_type(4)));

template<bool INT>
__device__ __forceinline__ void load_row(const float* __restrict__ X, int row,
                                         int j0, int lane, f32x4& v, float& ev)
{
    ev = 0.f;
    if (INT || (unsigned)row < (unsigned)HD) {
        const float* rp = X + (size_t)row * HD;
        v = *reinterpret_cast<const f32x4*>(rp + j0);
        const int eoff = (lane == 0) ? (j0 - 1) : (j0 + 4);
        bool need = (lane == 0) || (lane == 63);
        if (!INT) need = need && (eoff >= 0) && (eoff < HD);
        if (need) ev = rp[eoff];          // single 2-lane masked load
    } else {
        v[0] = 0.f; v[1] = 0.f; v[2] = 0.f; v[3] = 0.f;  // OOB row -> zeros
    }
}

__device__ __forceinline__ void make_x(const f32x4 v, const float ev, int lane,
                                       float x[6])
{
    float lft = __shfl_up(v[3], 1);       // lane l-1's v.w
    float rgt = __shfl_down(v[0], 1);     // lane l+1's v.x
    if (lane == 0)  lft = ev;
    if (lane == 63) rgt = ev;
    x[0] = lft; x[1] = v[0]; x[2] = v[1]; x[3] = v[2]; x[4] = v[3]; x[5] = rgt;
}

template<bool INT>
__device__ __forceinline__ void y1_row(const float xa[6], const float xb[6],
                                       float w00, float w01, float w10, float w11,
                                       bool pv, bool lv, bool rv, float y[5])
{
    #pragma unroll
    for (int q = 0; q < 5; ++q) {
        float v = w00 * xa[q] + w01 * xa[q + 1]
                + w10 * xb[q] + w11 * xb[q + 1];
        if (!INT) {
            const bool ok = pv && (q != 0 || lv) && (q != 4 || rv);
            v = ok ? v : 0.f;
        }
        y[q] = v;
    }
}

template<bool INT>
__device__ __forceinline__ void tile(const float* __restrict__ X,
                                     float* __restrict__ Y,
                                     int i0, int j0, int lane,
                                     float w00, float w01, float w10, float w11)
{
    const bool lv = INT || (j0 > 0);
    const bool rv = INT || (j0 + 4 < HD);

    // Issue 4 row-loads up front: rows i0-1, i0, i0+1, i0+2 (4KB in flight).
    f32x4 vA, vB, r1, r2; float eA, eB, e1, e2;
    load_row<INT>(X, i0 - 1, j0, lane, vA, eA);
    load_row<INT>(X, i0,     j0, lane, vB, eB);
    load_row<INT>(X, i0 + 1, j0, lane, r1, e1);
    load_row<INT>(X, i0 + 2, j0, lane, r2, e2);

    float xa[6], xb[6], xc[6];
    make_x(vA, eA, lane, xa);      // row i0-1
    make_x(vB, eB, lane, xb);      // row i0

    float y1p[5], y1c[5];
    y1_row<INT>(xa, xb, w00, w01, w10, w11, (i0 > 0), lv, rv, y1p);

    #pragma unroll
    for (int r = 0; r < RB; ++r) {
        const int i = i0 + r;

        f32x4 vN = r2; float eN = e2;               // default keeps regs defined
        if (r < RB - 2)                             // prefetch row i+3
            load_row<INT>(X, i + 3, j0, lane, vN, eN);

        make_x(r1, e1, lane, xc);                   // row i+1 (waits r1 only;
                                                    //  r2, vN still in flight)
        y1_row<INT>(xb, xc, w00, w01, w10, w11, (i < HD - 1), lv, rv, y1c);

        // y2[i,j0+t] = W00*y1(i,j)+W01*y1(i,j-1)+W10*y1(i-1,j)+W11*y1(i-1,j-1)
        f32x4 o;
        o[0] = w00 * y1c[1] + w01 * y1c[0] + w10 * y1p[1] + w11 * y1p[0];
        o[1] = w00 * y1c[2] + w01 * y1c[1] + w10 * y1p[2] + w11 * y1p[1];
        o[2] = w00 * y1c[3] + w01 * y1c[2] + w10 * y1p[3] + w11 * y1p[2];
        o[3] = w00 * y1c[4] + w01 * y1c[3] + w10 * y1p[4] + w11 * y1p[3];
        __builtin_nontemporal_store(o,
            reinterpret_cast<f32x4*>(Y + (size_t)i * HD + j0));

        #pragma unroll
        for (int q = 0; q < 5; ++q) y1p[q] = y1c[q];   // rename, not copy
        #pragma unroll
        for (int c = 0; c < 6; ++c) xb[c] = xc[c];
        r1 = r2; e1 = e2;                              // advance raw queue
        r2 = vN; e2 = eN;
    }
}

__global__ __launch_bounds__(256, 8) void fused_conv_kernel(
    const float* __restrict__ X, const float* __restrict__ Wk,
    float* __restrict__ Y)
{
    const int idx  = blockIdx.x * blockDim.x + threadIdx.x;
    const int i0   = (idx >> 10) * RB;          // output row-strip start
    const int j0   = (idx & 1023) << 2;         // first output col of quad
    const int lane = threadIdx.x & 63;

    const float w00 = Wk[0], w01 = Wk[1], w10 = Wk[2], w11 = Wk[3];

    // Wave-uniform interior test (wave spans 64 consecutive quads; jw0 is
    // lane-0's j0). Interior: all X rows i0-1..i0+RB in bounds, all y1 rows
    // valid, no lane touching col 0 or col HD-4.
    const int jw0 = ((idx & 1023) - lane) << 2;
    const bool interior = (i0 >= RB) && (i0 <= HD - 2 * RB) &&
                          (jw0 != 0) && (jw0 != HD - 256);

    if (interior) tile<true >(X, Y, i0, j0, lane, w00, w01, w10, w11);
    else          tile<false>(X, Y, i0, j0, lane, w00, w01, w10, w11);
}

extern "C" void kernel_launch(void* const* d_in, const int* in_sizes, int n_in,
                              void* d_out, int out_size, void* d_ws, size_t ws_size,
                              hipStream_t stream) {
    const float* X  = (const float*)d_in[0];
    const float* Wk = (const float*)d_in[1];
    float* Y        = (float*)d_out;

    const int total_threads = (HD / RB) * (HD / 4);   // 512 * 1024
    const int block = 256;
    const int grid  = total_threads / block;          // 2048 blocks
    fused_conv_kernel<<<grid, block, 0, stream>>>(X, Wk, Y);
}

// Round 14
// 111.883 us; speedup vs baseline: 1.0721x; 1.0721x over previous
//
#include <hip/hip_runtime.h>

// Fused: y1 = valid cross-corr(X,W) [4095x4095]; y2 = transposed-conv(y1,W) [4096x4096]
//   y2[i,j] = sum_{a,b} W[a,b]*y1(i-a,j-b), y1 masked to [0,4095)^2
//   y1(p,q) = W00*X[p][q] + W01*X[p][q+1] + W10*X[p+1][q] + W11*X[p+1][q+1]
//
// R11 post-mortem: __launch_bounds__(256,8) forced VGPR<=64 but live state is
// ~71 VGPR -> spills -> kernel regressed ~31->~35us. This version: identical
// structure (depth-2 prefetch, interior fast path), launch bounds relaxed to
// (256,4) -> 128 VGPR budget, no spills, 16 waves/CU (40KB in flight >> 9KB
// needed). Single-variable A/B vs R11.

#define HD 4096
#define RB 8       // output rows per thread

typedef float f32x4 __attribute__((ext_vector_type(4)));

template<bool INT>
__device__ __forceinline__ void load_row(const float* __restrict__ X, int row,
                                         int j0, int lane, f32x4& v, float& ev)
{
    ev = 0.f;
    if (INT || (unsigned)row < (unsigned)HD) {
        const float* rp = X + (size_t)row * HD;
        v = *reinterpret_cast<const f32x4*>(rp + j0);
        const int eoff = (lane == 0) ? (j0 - 1) : (j0 + 4);
        bool need = (lane == 0) || (lane == 63);
        if (!INT) need = need && (eoff >= 0) && (eoff < HD);
        if (need) ev = rp[eoff];          // single 2-lane masked load
    } else {
        v[0] = 0.f; v[1] = 0.f; v[2] = 0.f; v[3] = 0.f;  // OOB row -> zeros
    }
}

__device__ __forceinline__ void make_x(const f32x4 v, const float ev, int lane,
                                       float x[6])
{
    float lft = __shfl_up(v[3], 1);       // lane l-1's v.w
    float rgt = __shfl_down(v[0], 1);     // lane l+1's v.x
    if (lane == 0)  lft = ev;
    if (lane == 63) rgt = ev;
    x[0] = lft; x[1] = v[0]; x[2] = v[1]; x[3] = v[2]; x[4] = v[3]; x[5] = rgt;
}

template<bool INT>
__device__ __forceinline__ void y1_row(const float xa[6], const float xb[6],
                                       float w00, float w01, float w10, float w11,
                                       bool pv, bool lv, bool rv, float y[5])
{
    #pragma unroll
    for (int q = 0; q < 5; ++q) {
        float v = w00 * xa[q] + w01 * xa[q + 1]
                + w10 * xb[q] + w11 * xb[q + 1];
        if (!INT) {
            const bool ok = pv && (q != 0 || lv) && (q != 4 || rv);
            v = ok ? v : 0.f;
        }
        y[q] = v;
    }
}

template<bool INT>
__device__ __forceinline__ void tile(const float* __restrict__ X,
                                     float* __restrict__ Y,
                                     int i0, int j0, int lane,
                                     float w00, float w01, float w10, float w11)
{
    const bool lv = INT || (j0 > 0);
    const bool rv = INT || (j0 + 4 < HD);

    // Issue 4 row-loads up front: rows i0-1, i0, i0+1, i0+2 (4KB in flight).
    f32x4 vA, vB, r1, r2; float eA, eB, e1, e2;
    load_row<INT>(X, i0 - 1, j0, lane, vA, eA);
    load_row<INT>(X, i0,     j0, lane, vB, eB);
    load_row<INT>(X, i0 + 1, j0, lane, r1, e1);
    load_row<INT>(X, i0 + 2, j0, lane, r2, e2);

    float xa[6], xb[6], xc[6];
    make_x(vA, eA, lane, xa);      // row i0-1
    make_x(vB, eB, lane, xb);      // row i0

    float y1p[5], y1c[5];
    y1_row<INT>(xa, xb, w00, w01, w10, w11, (i0 > 0), lv, rv, y1p);

    #pragma unroll
    for (int r = 0; r < RB; ++r) {
        const int i = i0 + r;

        f32x4 vN = r2; float eN = e2;               // default keeps regs defined
        if (r < RB - 2)                             // prefetch row i+3
            load_row<INT>(X, i + 3, j0, lane, vN, eN);

        make_x(r1, e1, lane, xc);                   // row i+1 (waits r1 only;
                                                    //  r2, vN still in flight)
        y1_row<INT>(xb, xc, w00, w01, w10, w11, (i < HD - 1), lv, rv, y1c);

        // y2[i,j0+t] = W00*y1(i,j)+W01*y1(i,j-1)+W10*y1(i-1,j)+W11*y1(i-1,j-1)
        f32x4 o;
        o[0] = w00 * y1c[1] + w01 * y1c[0] + w10 * y1p[1] + w11 * y1p[0];
        o[1] = w00 * y1c[2] + w01 * y1c[1] + w10 * y1p[2] + w11 * y1p[1];
        o[2] = w00 * y1c[3] + w01 * y1c[2] + w10 * y1p[3] + w11 * y1p[2];
        o[3] = w00 * y1c[4] + w01 * y1c[3] + w10 * y1p[4] + w11 * y1p[3];
        __builtin_nontemporal_store(o,
            reinterpret_cast<f32x4*>(Y + (size_t)i * HD + j0));

        #pragma unroll
        for (int q = 0; q < 5; ++q) y1p[q] = y1c[q];   // rename, not copy
        #pragma unroll
        for (int c = 0; c < 6; ++c) xb[c] = xc[c];
        r1 = r2; e1 = e2;                              // advance raw queue
        r2 = vN; e2 = eN;
    }
}

__global__ __launch_bounds__(256, 4) void fused_conv_kernel(
    const float* __restrict__ X, const float* __restrict__ Wk,
    float* __restrict__ Y)
{
    const int idx  = blockIdx.x * blockDim.x + threadIdx.x;
    const int i0   = (idx >> 10) * RB;          // output row-strip start
    const int j0   = (idx & 1023) << 2;         // first output col of quad
    const int lane = threadIdx.x & 63;

    const float w00 = Wk[0], w01 = Wk[1], w10 = Wk[2], w11 = Wk[3];

    // Wave-uniform interior test (wave spans 64 consecutive quads; jw0 is
    // lane-0's j0). Interior: all X rows i0-1..i0+RB in bounds, all y1 rows
    // valid, no lane touching col 0 or col HD-4.
    const int jw0 = ((idx & 1023) - lane) << 2;
    const bool interior = (i0 >= RB) && (i0 <= HD - 2 * RB) &&
                          (jw0 != 0) && (jw0 != HD - 256);

    if (interior) tile<true >(X, Y, i0, j0, lane, w00, w01, w10, w11);
    else          tile<false>(X, Y, i0, j0, lane, w00, w01, w10, w11);
}

extern "C" void kernel_launch(void* const* d_in, const int* in_sizes, int n_in,
                              void* d_out, int out_size, void* d_ws, size_t ws_size,
                              hipStream_t stream) {
    const float* X  = (const float*)d_in[0];
    const float* Wk = (const float*)d_in[1];
    float* Y        = (float*)d_out;

    const int total_threads = (HD / RB) * (HD / 4);   // 512 * 1024
    const int block = 256;
    const int grid  = total_threads / block;          // 2048 blocks
    fused_conv_kernel<<<grid, block, 0, stream>>>(X, Wk, Y);
}